// Round 16
// baseline (78.958 us; speedup 1.0000x reference)
//
#include <hip/hip_runtime.h>
#include <math.h>

#define BB 8
#define NN 512
#define FF 32
#define HH 64
#define NEG_BIG (-1.0e30f)

__device__ __forceinline__ float lane_bcast(float v, int l) {
    return __int_as_float(__builtin_amdgcn_readlane(__float_as_int(v), l));
}

// ---------------------------------------------------------------------------
// encode: h = relu(x@W_enc+b); zi = h@W_e1[:H]+b_e1 (folded); zjT2 = second
// projection TRANSPOSED + k-pair interleaved (float2 at [b][k>>1][n]).
// ---------------------------------------------------------------------------
__global__ __launch_bounds__(256) void encode_kernel(
    const float* __restrict__ x, const float* __restrict__ W_enc,
    const float* __restrict__ b_enc, const float* __restrict__ W_e1,
    const float* __restrict__ b_e1,
    float* __restrict__ h, float* __restrict__ zi, float* __restrict__ zjT2)
{
    const int t = threadIdx.x;
    const int hh = t & 63;
    const int qu = __builtin_amdgcn_readfirstlane(t >> 6);
    const int gR = blockIdx.x * 4 + qu;           // 0..B*N-1

    const float xv = x[gR * FF + (hh & 31)];      // coalesced; lanes 32+ dup
    float acc = b_enc[hh];
#pragma unroll 8
    for (int k = 0; k < FF; ++k)
        acc = fmaf(lane_bcast(xv, k), W_enc[k * HH + hh], acc);
    const float hval = fmaxf(acc, 0.f);
    h[gR * HH + hh] = hval;

    float z1 = b_e1[hh], z2 = 0.f;
#pragma unroll 8
    for (int k = 0; k < HH; ++k) {
        const float hk = lane_bcast(hval, k);
        z1 = fmaf(hk, W_e1[k * HH + hh], z1);
        z2 = fmaf(hk, W_e1[(HH + k) * HH + hh], z2);
    }
    zi[gR * HH + hh] = z1;
    const int b = gR >> 9, n = gR & (NN - 1);
    zjT2[(((size_t)b * 32 + (hh >> 1)) * NN + n) * 2 + (hh & 1)] = z2;
}

// ---------------------------------------------------------------------------
// adj (standalone): 1024 blocks x 512 thr, (512,8) = 32 waves/CU.
// block = (b, 4 rows); wave w = j-slice [64w, 64w+64), lane tj -> j.
// Edge loop: zjT2 8B/lane coalesced; zi & W_e2 block-uniform s_loads.
// Also inits out[b] = b_out (stream order precedes layer-2 atomics).
// ---------------------------------------------------------------------------
__global__ __launch_bounds__(512, 8) void adj_kernel(
    const float* __restrict__ zi, const float* __restrict__ zjT2,
    const float* __restrict__ We2, const float* __restrict__ be2,
    const float* __restrict__ b_out,
    float* __restrict__ adjw, float* __restrict__ out)
{
    const int b  = blockIdx.x >> 7;
    const int i0 = (blockIdx.x & 127) << 2;
    const int t  = threadIdx.x;
    const int tj = t & 63;
    const int w  = __builtin_amdgcn_readfirstlane(t >> 6);   // 0..7
    const int gR0 = b * NN + i0;
    const int j   = 64 * w + tj;

    __shared__ float redm[8][4], reds[8][4];

    if (blockIdx.x < BB && t == 0) out[blockIdx.x] = b_out[0];  // init for atomics

    const float2* zi2 = (const float2*)(zi + (size_t)gR0 * HH);  // s_load
    const float2* we2 = (const float2*)We2;                      // s_load
    const float2* zt2 = (const float2*)zjT2 + (size_t)b * 32 * NN + j;

    float2 a2[4];
#pragma unroll
    for (int r = 0; r < 4; ++r) a2[r] = make_float2(0.f, 0.f);
#pragma unroll 8
    for (int k2 = 0; k2 < 32; ++k2) {
        const float2 z = zt2[(size_t)k2 * NN];     // 8B coalesced
        const float2 wk = we2[k2];                 // s_load
#pragma unroll
        for (int r = 0; r < 4; ++r) {
            const float2 zv = zi2[r * 32 + k2];    // s_load
            a2[r].x = fmaf(fmaxf(zv.x + z.x, 0.f), wk.x, a2[r].x);
            a2[r].y = fmaf(fmaxf(zv.y + z.y, 0.f), wk.y, a2[r].y);
        }
    }
    const float bias2 = be2[0];
    float acc[4];
#pragma unroll
    for (int r = 0; r < 4; ++r) {
        acc[r] = a2[r].x + a2[r].y + bias2;
        if (j == i0 + r) acc[r] = NEG_BIG;         // diag mask
    }

    // softmax over j: in-wave shfl + cross-wave (8 slices) LDS reduce
#pragma unroll
    for (int r = 0; r < 4; ++r) {
        float m = acc[r];
#pragma unroll
        for (int off = 32; off >= 1; off >>= 1)
            m = fmaxf(m, __shfl_xor(m, off));
        if (tj == 0) redm[w][r] = m;
    }
    __syncthreads();
    float M[4];
#pragma unroll
    for (int r = 0; r < 4; ++r) {
        float m = redm[0][r];
#pragma unroll
        for (int p = 1; p < 8; ++p) m = fmaxf(m, redm[p][r]);
        M[r] = m;
    }
    float e[4];
#pragma unroll
    for (int r = 0; r < 4; ++r) {
        e[r] = __expf(acc[r] - M[r]);
        float s = e[r];
#pragma unroll
        for (int off = 32; off >= 1; off >>= 1) s += __shfl_xor(s, off);
        if (tj == 0) reds[w][r] = s;
    }
    __syncthreads();
#pragma unroll
    for (int r = 0; r < 4; ++r) {
        float s = reds[0][r];
#pragma unroll
        for (int p = 1; p < 8; ++p) s += reds[p][r];
        adjw[(size_t)(gR0 + r) * NN + j] = e[r] * (1.0f / s);
    }
}

// ---------------------------------------------------------------------------
// layer<LAST>: 1024 blocks x 512 thr, (512,8) = 32 waves/CU.
// block = (b, 4 rows).  WAVE SPECIALIZATION (this round's change):
//   waves 0-3: phase A (m partials, 128-j slice each; adj via s_load)
//   waves 4-7: CONCURRENTLY compute gh = h@Whh gates for row w-4 (depends
//              only on h_in -> hoisted off the critical path; its Whh
//              stream overlaps phase A instead of serializing after B).
// barrier; waves 0-3: B (m reduce + mm GEMM); barrier;
// phase C = gi half only: wave (kh=w>>2, r=w&3), 96 loads each; barrier;
// finalize waves 0-3 (gi from GPI, gh from GHL).
// LAST: per-block readout fold via one scalar atomicAdd (out pre-inited).
// ---------------------------------------------------------------------------
template <int LAST>
__global__ __launch_bounds__(512, 8) void layer_kernel(
    const float* __restrict__ adjr, const float* __restrict__ h_in,
    const float* __restrict__ Wmsg, const float* __restrict__ bmsg,
    const float* __restrict__ Wih, const float* __restrict__ bih,
    const float* __restrict__ Whh, const float* __restrict__ bhh,
    const float* __restrict__ Wout,
    float* __restrict__ h_out, float* __restrict__ out)
{
    const int b  = blockIdx.x >> 7;
    const int i0 = (blockIdx.x & 127) << 2;
    const int t  = threadIdx.x;
    const int tj = t & 63;
    const int w  = __builtin_amdgcn_readfirstlane(t >> 6);   // 0..7
    const int gR0 = b * NN + i0;

    __shared__ float RED[4][4][66];      // A partials [slice][row][c]
    __shared__ float GHL[4][3][66];      // gh gates   [row][gate][c]
    __shared__ float GPI[2][4][3][66];   // gi partials [kh][row][gate][c]
    __shared__ float mml[4][66];

    if (w < 4) {
        //=== phase A: all 4 rows x j-slice [128w, 128w+128) =================
        const float* hq = h_in + ((size_t)b * NN + 128 * w) * HH + tj;
        const float* a0 = adjr + (size_t)(gR0 + 0) * NN + 128 * w;
        const float* a1 = adjr + (size_t)(gR0 + 1) * NN + 128 * w;
        const float* a2 = adjr + (size_t)(gR0 + 2) * NN + 128 * w;
        const float* a3 = adjr + (size_t)(gR0 + 3) * NN + 128 * w;
        float mac[4] = {0.f, 0.f, 0.f, 0.f};
#pragma unroll 8
        for (int jj = 0; jj < 128; ++jj) {
            const float hv = hq[(size_t)jj * HH];
            mac[0] = fmaf(a0[jj], hv, mac[0]);
            mac[1] = fmaf(a1[jj], hv, mac[1]);
            mac[2] = fmaf(a2[jj], hv, mac[2]);
            mac[3] = fmaf(a3[jj], hv, mac[3]);
        }
#pragma unroll
        for (int r = 0; r < 4; ++r) RED[w][r][tj] = mac[r];
    } else {
        //=== gh gates for row w-4 (overlapped with phase A) =================
        const int rr = w - 4;
        const float hreg = h_in[(size_t)(gR0 + rr) * HH + tj];
        float g3 = bhh[tj], g4 = bhh[64 + tj], g5 = bhh[128 + tj];
#pragma unroll 4
        for (int k = 0; k < HH; ++k) {
            const float sh = lane_bcast(hreg, k);
            const float* wh = Whh + (size_t)k * 192;
            g3 = fmaf(sh, wh[tj], g3);
            g4 = fmaf(sh, wh[64 + tj], g4);
            g5 = fmaf(sh, wh[128 + tj], g5);
        }
        GHL[rr][0][tj] = g3;
        GHL[rr][1][tj] = g4;
        GHL[rr][2][tj] = g5;
    }
    __syncthreads();

    //=== phase B: waves 0-3, wave w = row w: m reduce + mm GEMM =============
    if (w < 4) {
        const float m = RED[0][w][tj] + RED[1][w][tj]
                      + RED[2][w][tj] + RED[3][w][tj];
        float mmv = bmsg[tj];
#pragma unroll 8
        for (int k = 0; k < HH; ++k)
            mmv = fmaf(lane_bcast(m, k), Wmsg[k * HH + tj], mmv);
        mml[w][tj] = fmaxf(mmv, 0.f);
    }
    __syncthreads();

    //=== phase C (gi only): wave = (kh = w>>2, r = w&3): 3 gates x 32 k =====
    {
        const int kh = w >> 2, r = w & 3;
        const float srcv = mml[r][tj];
        float g0 = kh ? 0.f : bih[tj];
        float g1 = kh ? 0.f : bih[64 + tj];
        float g2 = kh ? 0.f : bih[128 + tj];
        const int k0 = kh * 32;
#pragma unroll 4
        for (int kk = 0; kk < 32; ++kk) {
            const float* wi = Wih + (size_t)(k0 + kk) * 192;
            const float s = lane_bcast(srcv, k0 + kk);
            g0 = fmaf(s, wi[tj], g0);
            g1 = fmaf(s, wi[64 + tj], g1);
            g2 = fmaf(s, wi[128 + tj], g2);
        }
        GPI[kh][r][0][tj] = g0;
        GPI[kh][r][1][tj] = g1;
        GPI[kh][r][2][tj] = g2;
    }
    __syncthreads();

    //=== finalize: waves 0-3, wave w = row w ================================
    float hnew = 0.f;
    if (w < 4) {
        const float hprev = h_in[(size_t)(gR0 + w) * HH + tj];
        const float ir  = GPI[0][w][0][tj] + GPI[1][w][0][tj];
        const float iz  = GPI[0][w][1][tj] + GPI[1][w][1][tj];
        const float inn = GPI[0][w][2][tj] + GPI[1][w][2][tj];
        const float hr  = GHL[w][0][tj];
        const float hz  = GHL[w][1][tj];
        const float hn  = GHL[w][2][tj];
        const float rg = 1.f / (1.f + __expf(-(ir + hr)));
        const float zg = 1.f / (1.f + __expf(-(iz + hz)));
        const float ng = tanhf(inn + rg * hn);
        hnew = (1.f - zg) * ng + zg * hprev;
        h_out[(size_t)(gR0 + w) * HH + tj] = hnew;
    }

    if (LAST) {   // readout fold: one scalar atomicAdd per block
        __syncthreads();                  // all GPI/mml reads complete
        if (w < 4) mml[w][tj] = hnew;
        __syncthreads();
        if (w == 0) {
            float v = (mml[0][tj] + mml[1][tj] + mml[2][tj] + mml[3][tj])
                      * (1.0f / NN) * Wout[tj];
#pragma unroll
            for (int off = 32; off >= 1; off >>= 1) v += __shfl_xor(v, off);
            if (tj == 0) atomicAdd(out + b, v);
        }
    }
}

extern "C" void kernel_launch(void* const* d_in, const int* in_sizes, int n_in,
                              void* d_out, int out_size, void* d_ws, size_t ws_size,
                              hipStream_t stream)
{
    const float* x     = (const float*)d_in[0];
    const float* W_enc = (const float*)d_in[1];
    const float* b_enc = (const float*)d_in[2];
    const float* W_e1  = (const float*)d_in[3];
    const float* b_e1  = (const float*)d_in[4];
    const float* W_e2  = (const float*)d_in[5];
    const float* b_e2  = (const float*)d_in[6];
    const float* W_msg = (const float*)d_in[7];
    const float* b_msg = (const float*)d_in[8];
    const float* W_ih  = (const float*)d_in[9];
    const float* b_ih  = (const float*)d_in[10];
    const float* W_hh  = (const float*)d_in[11];
    const float* b_hh  = (const float*)d_in[12];
    const float* W_out = (const float*)d_in[13];
    const float* b_out = (const float*)d_in[14];
    float* out = (float*)d_out;

    float* ws   = (float*)d_ws;
    float* h0   = ws;
    float* h1   = h0 + BB * NN * HH;
    float* zi   = h1 + BB * NN * HH;
    float* zjT2 = zi + BB * NN * HH;        // float2[B][32][N]
    float* adjw = zjT2 + BB * NN * HH;

    encode_kernel<<<BB * NN / 4, 256, 0, stream>>>(
        x, W_enc, b_enc, W_e1, b_e1, h0, zi, zjT2);

    adj_kernel<<<BB * (NN / 4), 512, 0, stream>>>(
        zi, zjT2, W_e2, b_e2, b_out, adjw, out);

    layer_kernel<0><<<BB * (NN / 4), 512, 0, stream>>>(
        adjw, h0, W_msg, b_msg, W_ih, b_ih, W_hh, b_hh, W_out, h1, out);
    layer_kernel<1><<<BB * (NN / 4), 512, 0, stream>>>(
        adjw, h1, W_msg + HH * HH, b_msg + HH,
        W_ih + HH * 3 * HH, b_ih + 3 * HH, W_hh + HH * 3 * HH, b_hh + 3 * HH,
        W_out, h0, out);
}

// Round 17
// 71.588 us; speedup vs baseline: 1.1030x; 1.1030x over previous
//
#include <hip/hip_runtime.h>
#include <math.h>

#define BB 8
#define NN 512
#define FF 32
#define HH 64
#define NEG_BIG (-1.0e30f)

__device__ __forceinline__ float lane_bcast(float v, int l) {
    return __int_as_float(__builtin_amdgcn_readlane(__float_as_int(v), l));
}

// ---------------------------------------------------------------------------
// encode: h = relu(x@W_enc+b); zi = h@W_e1[:H]+b_e1 (folded); zjT2 = second
// projection TRANSPOSED + k-pair interleaved (float2 at [b][k>>1][n]).
// ---------------------------------------------------------------------------
__global__ __launch_bounds__(256) void encode_kernel(
    const float* __restrict__ x, const float* __restrict__ W_enc,
    const float* __restrict__ b_enc, const float* __restrict__ W_e1,
    const float* __restrict__ b_e1,
    float* __restrict__ h, float* __restrict__ zi, float* __restrict__ zjT2)
{
    const int t = threadIdx.x;
    const int hh = t & 63;
    const int qu = __builtin_amdgcn_readfirstlane(t >> 6);
    const int gR = blockIdx.x * 4 + qu;           // 0..B*N-1

    const float xv = x[gR * FF + (hh & 31)];      // coalesced; lanes 32+ dup
    float acc = b_enc[hh];
#pragma unroll 8
    for (int k = 0; k < FF; ++k)
        acc = fmaf(lane_bcast(xv, k), W_enc[k * HH + hh], acc);
    const float hval = fmaxf(acc, 0.f);
    h[gR * HH + hh] = hval;

    float z1 = b_e1[hh], z2 = 0.f;
#pragma unroll 8
    for (int k = 0; k < HH; ++k) {
        const float hk = lane_bcast(hval, k);
        z1 = fmaf(hk, W_e1[k * HH + hh], z1);
        z2 = fmaf(hk, W_e1[(HH + k) * HH + hh], z2);
    }
    zi[gR * HH + hh] = z1;
    const int b = gR >> 9, n = gR & (NN - 1);
    zjT2[(((size_t)b * 32 + (hh >> 1)) * NN + n) * 2 + (hh & 1)] = z2;
}

// ---------------------------------------------------------------------------
// adj (standalone, R15-identical): 1024 blocks x 512 thr, (512,8).
// block = (b, 4 rows); wave w = j-slice [64w, 64w+64), lane tj -> j.
// Edge loop: zjT2 8B/lane coalesced; zi & W_e2 block-uniform s_loads.
// Also inits out[b] = b_out (stream order precedes layer-2 atomics).
// ---------------------------------------------------------------------------
__global__ __launch_bounds__(512, 8) void adj_kernel(
    const float* __restrict__ zi, const float* __restrict__ zjT2,
    const float* __restrict__ We2, const float* __restrict__ be2,
    const float* __restrict__ b_out,
    float* __restrict__ adjw, float* __restrict__ out)
{
    const int b  = blockIdx.x >> 7;
    const int i0 = (blockIdx.x & 127) << 2;
    const int t  = threadIdx.x;
    const int tj = t & 63;
    const int w  = __builtin_amdgcn_readfirstlane(t >> 6);   // 0..7
    const int gR0 = b * NN + i0;
    const int j   = 64 * w + tj;

    __shared__ float redm[8][4], reds[8][4];

    if (blockIdx.x < BB && t == 0) out[blockIdx.x] = b_out[0];  // init for atomics

    const float2* zi2 = (const float2*)(zi + (size_t)gR0 * HH);  // s_load
    const float2* we2 = (const float2*)We2;                      // s_load
    const float2* zt2 = (const float2*)zjT2 + (size_t)b * 32 * NN + j;

    float2 a2[4];
#pragma unroll
    for (int r = 0; r < 4; ++r) a2[r] = make_float2(0.f, 0.f);
#pragma unroll 8
    for (int k2 = 0; k2 < 32; ++k2) {
        const float2 z = zt2[(size_t)k2 * NN];     // 8B coalesced
        const float2 wk = we2[k2];                 // s_load
#pragma unroll
        for (int r = 0; r < 4; ++r) {
            const float2 zv = zi2[r * 32 + k2];    // s_load
            a2[r].x = fmaf(fmaxf(zv.x + z.x, 0.f), wk.x, a2[r].x);
            a2[r].y = fmaf(fmaxf(zv.y + z.y, 0.f), wk.y, a2[r].y);
        }
    }
    const float bias2 = be2[0];
    float acc[4];
#pragma unroll
    for (int r = 0; r < 4; ++r) {
        acc[r] = a2[r].x + a2[r].y + bias2;
        if (j == i0 + r) acc[r] = NEG_BIG;         // diag mask
    }

    // softmax over j: in-wave shfl + cross-wave (8 slices) LDS reduce
#pragma unroll
    for (int r = 0; r < 4; ++r) {
        float m = acc[r];
#pragma unroll
        for (int off = 32; off >= 1; off >>= 1)
            m = fmaxf(m, __shfl_xor(m, off));
        if (tj == 0) redm[w][r] = m;
    }
    __syncthreads();
    float M[4];
#pragma unroll
    for (int r = 0; r < 4; ++r) {
        float m = redm[0][r];
#pragma unroll
        for (int p = 1; p < 8; ++p) m = fmaxf(m, redm[p][r]);
        M[r] = m;
    }
    float e[4];
#pragma unroll
    for (int r = 0; r < 4; ++r) {
        e[r] = __expf(acc[r] - M[r]);
        float s = e[r];
#pragma unroll
        for (int off = 32; off >= 1; off >>= 1) s += __shfl_xor(s, off);
        if (tj == 0) reds[w][r] = s;
    }
    __syncthreads();
#pragma unroll
    for (int r = 0; r < 4; ++r) {
        float s = reds[0][r];
#pragma unroll
        for (int p = 1; p < 8; ++p) s += reds[p][r];
        adjw[(size_t)(gR0 + r) * NN + j] = e[r] * (1.0f / s);
    }
}

// ---------------------------------------------------------------------------
// layer<LAST> (R15 structure; B/C broadcasts moved from v_readlane (VALU)
// to wave-uniform ds_read (LDS pipe) -- ~96 VALU inst/wave freed):
// 1024 blocks x 512 thr, (512,8) = 32 waves/CU.  block = (b, 4 rows).
// A: all 8 waves, 64-j slice each, adj via s_load, partials -> RED.
// B: waves 0-3 = row w: m reduce -> mraw, mm GEMM reads mraw[w][k] uniform.
// C: (half,kh,rq) split; source rows read hol/mml[row][k] uniform.
// LAST: per-block readout fold via one scalar atomicAdd (out pre-inited).
// ---------------------------------------------------------------------------
template <int LAST>
__global__ __launch_bounds__(512, 8) void layer_kernel(
    const float* __restrict__ adjr, const float* __restrict__ h_in,
    const float* __restrict__ Wmsg, const float* __restrict__ bmsg,
    const float* __restrict__ Wih, const float* __restrict__ bih,
    const float* __restrict__ Whh, const float* __restrict__ bhh,
    const float* __restrict__ Wout,
    float* __restrict__ h_out, float* __restrict__ out)
{
    const int b  = blockIdx.x >> 7;
    const int i0 = (blockIdx.x & 127) << 2;
    const int t  = threadIdx.x;
    const int tj = t & 63;
    const int w  = __builtin_amdgcn_readfirstlane(t >> 6);   // 0..7
    const int gR0 = b * NN + i0;

    __shared__ float smem[3168];                  // union RED[8][4][66]/GP[2][2][4][3][66]
    __shared__ float mml[4][66];
    __shared__ float mraw[4][66];
    __shared__ float hol[4][66];
#define RED(p, r, c)        smem[(((p) * 4) + (r)) * 66 + (c)]
#define GP(h2, k2, r, g, c) smem[(((((h2) * 2 + (k2)) * 4 + (r)) * 3 + (g)) * 66) + (c)]

    if (w < 4) hol[w][tj] = h_in[(size_t)(gR0 + w) * HH + tj];

    //=== phase A: m partials (adj via s_load, h coalesced) ==================
    {
        const float* hq = h_in + ((size_t)b * NN + 64 * w) * HH + tj;
        const float* a0 = adjr + (size_t)(gR0 + 0) * NN + 64 * w;
        const float* a1 = adjr + (size_t)(gR0 + 1) * NN + 64 * w;
        const float* a2 = adjr + (size_t)(gR0 + 2) * NN + 64 * w;
        const float* a3 = adjr + (size_t)(gR0 + 3) * NN + 64 * w;
        float mac[4] = {0.f, 0.f, 0.f, 0.f};
#pragma unroll 8
        for (int jj = 0; jj < 64; ++jj) {
            const float hv = hq[(size_t)jj * HH];
            mac[0] = fmaf(a0[jj], hv, mac[0]);
            mac[1] = fmaf(a1[jj], hv, mac[1]);
            mac[2] = fmaf(a2[jj], hv, mac[2]);
            mac[3] = fmaf(a3[jj], hv, mac[3]);
        }
#pragma unroll
        for (int r = 0; r < 4; ++r) RED(w, r, tj) = mac[r];
    }
    __syncthreads();

    //=== phase B: waves 0-3, wave w = row w: m reduce + mm GEMM =============
    if (w < 4) {
        float m = RED(0, w, tj);
#pragma unroll
        for (int p = 1; p < 8; ++p) m += RED(p, w, tj);
        mraw[w][tj] = m;                 // own-wave write; read back uniform
        float mmv = bmsg[tj];
#pragma unroll 8
        for (int k = 0; k < HH; ++k)
            mmv = fmaf(mraw[w][k], Wmsg[k * HH + tj], mmv);   // LDS broadcast
        mml[w][tj] = fmaxf(mmv, 0.f);
    }
    __syncthreads();   // mml ready; RED dead -> GP overlay legal

    //=== phase C: wave = (half, kh, rq): 3 gates x 2 rows x 32 k ============
    {
        const int half = w >> 2, kh = (w >> 1) & 1, rq = w & 1;
        const float* Wg = half ? Whh : Wih;
        const float* bg = half ? bhh : bih;
        const float (*S)[66] = half ? (const float (*)[66])hol
                                    : (const float (*)[66])mml;
        float g0[2], g1[2], g2[2];
#pragma unroll
        for (int r = 0; r < 2; ++r) {
            g0[r] = kh ? 0.f : bg[tj];
            g1[r] = kh ? 0.f : bg[64 + tj];
            g2[r] = kh ? 0.f : bg[128 + tj];
        }
        const int k0 = kh * 32;
#pragma unroll 4
        for (int kk = 0; kk < 32; ++kk) {
            const float* wk = Wg + (size_t)(k0 + kk) * 192;
            const float w0 = wk[tj], w1 = wk[64 + tj], w2 = wk[128 + tj];
#pragma unroll
            for (int r = 0; r < 2; ++r) {
                const float s = S[rq * 2 + r][k0 + kk];       // LDS broadcast
                g0[r] = fmaf(s, w0, g0[r]);
                g1[r] = fmaf(s, w1, g1[r]);
                g2[r] = fmaf(s, w2, g2[r]);
            }
        }
#pragma unroll
        for (int r = 0; r < 2; ++r) {
            GP(half, kh, rq * 2 + r, 0, tj) = g0[r];
            GP(half, kh, rq * 2 + r, 1, tj) = g1[r];
            GP(half, kh, rq * 2 + r, 2, tj) = g2[r];
        }
    }
    __syncthreads();

    //=== finalize: waves 0-3, wave w = row w ================================
    float hnew = 0.f;
    if (w < 4) {
        const float ir  = GP(0, 0, w, 0, tj) + GP(0, 1, w, 0, tj);
        const float iz  = GP(0, 0, w, 1, tj) + GP(0, 1, w, 1, tj);
        const float inn = GP(0, 0, w, 2, tj) + GP(0, 1, w, 2, tj);
        const float hr  = GP(1, 0, w, 0, tj) + GP(1, 1, w, 0, tj);
        const float hz  = GP(1, 0, w, 1, tj) + GP(1, 1, w, 1, tj);
        const float hn  = GP(1, 0, w, 2, tj) + GP(1, 1, w, 2, tj);
        const float rg = 1.f / (1.f + __expf(-(ir + hr)));
        const float zg = 1.f / (1.f + __expf(-(iz + hz)));
        const float ng = tanhf(inn + rg * hn);
        hnew = (1.f - zg) * ng + zg * hol[w][tj];
        h_out[(size_t)(gR0 + w) * HH + tj] = hnew;
    }

    if (LAST) {   // readout fold: one scalar atomicAdd per block
        __syncthreads();                  // phase C mml reads complete
        if (w < 4) mml[w][tj] = hnew;
        __syncthreads();
        if (w == 0) {
            float v = (mml[0][tj] + mml[1][tj] + mml[2][tj] + mml[3][tj])
                      * (1.0f / NN) * Wout[tj];
#pragma unroll
            for (int off = 32; off >= 1; off >>= 1) v += __shfl_xor(v, off);
            if (tj == 0) atomicAdd(out + b, v);
        }
    }
#undef RED
#undef GP
}

extern "C" void kernel_launch(void* const* d_in, const int* in_sizes, int n_in,
                              void* d_out, int out_size, void* d_ws, size_t ws_size,
                              hipStream_t stream)
{
    const float* x     = (const float*)d_in[0];
    const float* W_enc = (const float*)d_in[1];
    const float* b_enc = (const float*)d_in[2];
    const float* W_e1  = (const float*)d_in[3];
    const float* b_e1  = (const float*)d_in[4];
    const float* W_e2  = (const float*)d_in[5];
    const float* b_e2  = (const float*)d_in[6];
    const float* W_msg = (const float*)d_in[7];
    const float* b_msg = (const float*)d_in[8];
    const float* W_ih  = (const float*)d_in[9];
    const float* b_ih  = (const float*)d_in[10];
    const float* W_hh  = (const float*)d_in[11];
    const float* b_hh  = (const float*)d_in[12];
    const float* W_out = (const float*)d_in[13];
    const float* b_out = (const float*)d_in[14];
    float* out = (float*)d_out;

    float* ws   = (float*)d_ws;
    float* h0   = ws;
    float* h1   = h0 + BB * NN * HH;
    float* zi   = h1 + BB * NN * HH;
    float* zjT2 = zi + BB * NN * HH;        // float2[B][32][N]
    float* adjw = zjT2 + BB * NN * HH;

    encode_kernel<<<BB * NN / 4, 256, 0, stream>>>(
        x, W_enc, b_enc, W_e1, b_e1, h0, zi, zjT2);

    adj_kernel<<<BB * (NN / 4), 512, 0, stream>>>(
        zi, zjT2, W_e2, b_e2, b_out, adjw, out);

    layer_kernel<0><<<BB * (NN / 4), 512, 0, stream>>>(
        adjw, h0, W_msg, b_msg, W_ih, b_ih, W_hh, b_hh, W_out, h1, out);
    layer_kernel<1><<<BB * (NN / 4), 512, 0, stream>>>(
        adjw, h1, W_msg + HH * HH, b_msg + HH,
        W_ih + HH * 3 * HH, b_ih + 3 * HH, W_hh + HH * 3 * HH, b_hh + 3 * HH,
        W_out, h0, out);
}